// Round 15
// baseline (148.749 us; speedup 1.0000x reference)
//
#include <hip/hip_runtime.h>
#include <hip/hip_bf16.h>
#include <math.h>

// B=2, C=128, H=W=64, heads=4, head_dim=32, kernel=7 (49 taps), depth=2.
// Inputs fp32, OUTPUT fp32. Intermediates bf16. MFMA GEMMs.
// R15: GEMM->GEMM fusion. 6 launches:
//   prep | qkv0 | attn0 | projqkv (proj0+qkv1, LDS-chained) | attn1 |
//   proj_ln (proj1+LayerNorm+NCHW store).
// ws: [y0/attn 2MB][qkv 6MB][wq 192KB][wp 64KB] = 8.25 MB. d_out untouched
// until proj_ln writes it.
#define PIX 8192
typedef __hip_bfloat16 bf16;
typedef __attribute__((ext_vector_type(8))) short short8;
typedef __attribute__((ext_vector_type(4))) float f32x4;

__device__ inline float bflo(unsigned u) { return __uint_as_float(u << 16); }
__device__ inline float bfhi(unsigned u) { return __uint_as_float(u & 0xffff0000u); }
__device__ inline unsigned short f2b(float f) {
  __hip_bfloat16 h = __float2bfloat16(f);
  return *reinterpret_cast<unsigned short*>(&h);
}
__device__ inline unsigned pack2(float a, float b) {
  return (unsigned)f2b(a) | ((unsigned)f2b(b) << 16);
}

// ---------- prep: transpose x -> y(bf16, NHWC) AND cvt weights to bf16 ----------
__global__ __launch_bounds__(256) void prep(const float* __restrict__ x,
                                            const float* __restrict__ qw,
                                            const float* __restrict__ pw,
                                            unsigned short* __restrict__ y,
                                            unsigned short* __restrict__ wq,
                                            unsigned short* __restrict__ wp) {
  int tid = threadIdx.x;
  if (blockIdx.x >= 128) {                     // weight convert: 384 blocks
    int idx = (blockIdx.x - 128) * 256 + tid;
    if (idx < 98304) wq[idx] = f2b(qw[idx]);
    if (idx < 32768) wp[idx] = f2b(pw[idx]);
    return;
  }
  __shared__ float tile[64][129];
  int blk = blockIdx.x;                        // b*64 + i
  int b = blk >> 6, i = blk & 63;
  const float* xbase = x + (size_t)b * 128 * 4096 + (size_t)i * 64;
  for (int idx = tid; idx < 8192; idx += 256) {
    int c = idx >> 6, j = idx & 63;
    tile[j][c] = xbase[(size_t)c * 4096 + j];
  }
  __syncthreads();
  unsigned short* yrow = y + (size_t)blk * 64 * 128;
  for (int idx = tid; idx < 8192; idx += 256) {
    int j = idx >> 7, c = idx & 127;
    yrow[idx] = f2b(tile[j][c]);
  }
}

// ---------- MFMA GEMM (qkv0): C[M,384] = A[M,128] * W^T + bias ----------
__global__ __launch_bounds__(256) void gemm_mfma(const unsigned short* __restrict__ A,
                                                 const unsigned short* __restrict__ W,
                                                 const float* __restrict__ bias,
                                                 unsigned short* __restrict__ Cmat,
                                                 int N) {
  int m0 = blockIdx.x * 64, n0 = blockIdx.y * 64;
  int tid = threadIdx.x;
  int w = tid >> 6, lane = tid & 63;
  int quad = lane >> 4, l16 = lane & 15;

  const short8* ap =
      (const short8*)(A + (size_t)(m0 + w * 16 + l16) * 128 + quad * 8);
  short8 a[4];
#pragma unroll
  for (int kc = 0; kc < 4; ++kc) a[kc] = ap[kc * 4];

  f32x4 acc[4];
#pragma unroll
  for (int nt = 0; nt < 4; ++nt) {
    const short8* bp =
        (const short8*)(W + (size_t)(n0 + nt * 16 + l16) * 128 + quad * 8);
    f32x4 c = {0.f, 0.f, 0.f, 0.f};
#pragma unroll
    for (int kc = 0; kc < 4; ++kc)
      c = __builtin_amdgcn_mfma_f32_16x16x32_bf16(a[kc], bp[kc * 4], c, 0, 0, 0);
    acc[nt] = c;
  }

#pragma unroll
  for (int nt = 0; nt < 4; ++nt) {
    int col = n0 + nt * 16 + l16;
    float bv = bias[col];
#pragma unroll
    for (int r = 0; r < 4; ++r) {
      int m = m0 + w * 16 + quad * 4 + r;
      Cmat[(size_t)m * N + col] = f2b(acc[nt][r] + bv);
    }
  }
}

// ---------- neighborhood attention v6 (unchanged from R14) ----------
#define RSTRIDE 72
__global__ __launch_bounds__(256, 2) void na_attn(const unsigned short* __restrict__ qkvp,
                                                  const float* __restrict__ rpb,
                                                  unsigned short* __restrict__ out) {
  __shared__ __align__(16) unsigned short kbuf[140 * RSTRIDE];
  __shared__ __align__(16) unsigned short vbuf[140 * RSTRIDE];
  __shared__ float rb[338];
  __shared__ float sc[64][52];

  int ti = blockIdx.x >> 4, tj = blockIdx.x & 15;   // 8 x 16 tiles of 8x4 px
  int hp = blockIdx.y;
  int bz = blockIdx.z;
  int tid = threadIdx.x;
  int bi0 = ti * 8 - 3, bj0 = tj * 4 - 3;           // halo origin

  for (int t = tid; t < 338; t += 256) rb[t] = rpb[hp * 338 + t];

  for (int t = tid; t < 2240; t += 256) {
    int row = t >> 4;            // 0..139
    int sub = t & 15;
    int isv = sub >> 3;          // 0=K, 1=V
    int c = sub & 7;
    int ri = row / 10, rj = row - ri * 10;
    int gi = bi0 + ri, gj = bj0 + rj;
    uint4 val = make_uint4(0, 0, 0, 0);
    if ((unsigned)gi < 64u && (unsigned)gj < 64u) {
      int pixn = (bz * 64 + gi) * 64 + gj;
      val = *(const uint4*)(qkvp + (size_t)pixn * 384 + 128 + isv * 128 +
                            hp * 64 + c * 8);
    }
    *(uint4*)((isv ? vbuf : kbuf) + row * RSTRIDE + c * 8) = val;
  }
  __syncthreads();

  int r = tid & 3;
  int hl = (tid >> 2) & 1;
  int px = tid >> 3;
  int ph = px * 2 + hl;
  int pi = px >> 2, pj = px & 3;
  int i = ti * 8 + pi, j = tj * 4 + pj;
  int si = min(max(i - 3, 0), 57), sj = min(max(j - 3, 0), 57);
  int li = si - bi0, lj = sj - bj0;
  int oi = i - si, oj = j - sj;
  int H = hp * 2 + hl;
  int pix = (bz * 64 + i) * 64 + j;

  const float scale = 0.17677669529663687f;   // 32^-0.5
  float q[8];
  {
    uint4 t = *(const uint4*)(qkvp + (size_t)pix * 384 + H * 32 + r * 8);
    q[0] = bflo(t.x) * scale;  q[1] = bfhi(t.x) * scale;
    q[2] = bflo(t.y) * scale;  q[3] = bfhi(t.y) * scale;
    q[4] = bflo(t.z) * scale;  q[5] = bfhi(t.z) * scale;
    q[6] = bflo(t.w) * scale;  q[7] = bfhi(t.w) * scale;
  }

  const unsigned short* kh = kbuf + hl * 32 + r * 8;
  const unsigned short* vh = vbuf + hl * 32 + r * 8;
  const float* rbh = rb + hl * 169;

#pragma unroll
  for (int p = 0; p < 7; ++p) {
#pragma unroll
    for (int qq = 0; qq < 7; ++qq) {
      int n = (li + p) * 10 + (lj + qq);
      uint4 t = *(const uint4*)(kh + n * RSTRIDE);
      float dot = q[0] * bflo(t.x) + q[1] * bfhi(t.x)
                + q[2] * bflo(t.y) + q[3] * bfhi(t.y)
                + q[4] * bflo(t.z) + q[5] * bfhi(t.z)
                + q[6] * bflo(t.w) + q[7] * bfhi(t.w);
      dot += __shfl_xor(dot, 1);
      dot += __shfl_xor(dot, 2);
      if (r == 0) sc[ph][p * 7 + qq] = dot + rbh[(p + 6 - oi) * 13 + (qq + 6 - oj)];
    }
  }
  __syncthreads();

  float m = -INFINITY;
#pragma unroll
  for (int n = 0; n < 49; ++n) m = fmaxf(m, sc[ph][n]);

  float sum = 0.f;
  float acc[8] = {0.f, 0.f, 0.f, 0.f, 0.f, 0.f, 0.f, 0.f};
#pragma unroll
  for (int p = 0; p < 7; ++p) {
#pragma unroll
    for (int qq = 0; qq < 7; ++qq) {
      float e = __expf(sc[ph][p * 7 + qq] - m);
      sum += e;
      int n = (li + p) * 10 + (lj + qq);
      uint4 t = *(const uint4*)(vh + n * RSTRIDE);
      acc[0] += e * bflo(t.x);  acc[1] += e * bfhi(t.x);
      acc[2] += e * bflo(t.y);  acc[3] += e * bfhi(t.y);
      acc[4] += e * bflo(t.z);  acc[5] += e * bfhi(t.z);
      acc[6] += e * bflo(t.w);  acc[7] += e * bfhi(t.w);
    }
  }
  float inv = 1.f / sum;
  uint4 t;
  t.x = pack2(acc[0] * inv, acc[1] * inv);
  t.y = pack2(acc[2] * inv, acc[3] * inv);
  t.z = pack2(acc[4] * inv, acc[5] * inv);
  t.w = pack2(acc[6] * inv, acc[7] * inv);
  *(uint4*)(out + (size_t)pix * 128 + H * 32 + r * 8) = t;
}

// ---------- fused proj(l0) + qkv(l1): block = 64 pixels, LDS-chained ----------
#define PSTRIDE 136
__global__ __launch_bounds__(256) void projqkv(const unsigned short* __restrict__ attnp,
                                               const unsigned short* __restrict__ wp0,
                                               const float* __restrict__ pb0,
                                               const unsigned short* __restrict__ wq1,
                                               const float* __restrict__ qb1,
                                               unsigned short* __restrict__ qkvout) {
  __shared__ __align__(16) unsigned short po[64 * PSTRIDE];
  int m0 = blockIdx.x * 64;
  int tid = threadIdx.x;
  int w = tid >> 6, lane = tid & 63;
  int quad = lane >> 4, l16 = lane & 15;

  // phase 1: proj -> LDS (rows = pixels, cols = channels)
  {
    const short8* ap =
        (const short8*)(attnp + (size_t)(m0 + w * 16 + l16) * 128 + quad * 8);
    short8 a[4];
#pragma unroll
    for (int kc = 0; kc < 4; ++kc) a[kc] = ap[kc * 4];
#pragma unroll
    for (int nt = 0; nt < 8; ++nt) {
      const short8* bp =
          (const short8*)(wp0 + (size_t)(nt * 16 + l16) * 128 + quad * 8);
      f32x4 c = {0.f, 0.f, 0.f, 0.f};
#pragma unroll
      for (int kc = 0; kc < 4; ++kc)
        c = __builtin_amdgcn_mfma_f32_16x16x32_bf16(a[kc], bp[kc * 4], c, 0, 0, 0);
      float bv = pb0[nt * 16 + l16];
#pragma unroll
      for (int r2 = 0; r2 < 4; ++r2)
        po[(w * 16 + quad * 4 + r2) * PSTRIDE + nt * 16 + l16] = f2b(c[r2] + bv);
    }
  }
  __syncthreads();

  // phase 2: qkv1 from LDS A-fragments
  {
    short8 a[4];
#pragma unroll
    for (int kc = 0; kc < 4; ++kc)
      a[kc] = *(const short8*)(po + (w * 16 + l16) * PSTRIDE + kc * 32 + quad * 8);
#pragma unroll
    for (int nt = 0; nt < 24; ++nt) {
      const short8* bp =
          (const short8*)(wq1 + (size_t)(nt * 16 + l16) * 128 + quad * 8);
      f32x4 c = {0.f, 0.f, 0.f, 0.f};
#pragma unroll
      for (int kc = 0; kc < 4; ++kc)
        c = __builtin_amdgcn_mfma_f32_16x16x32_bf16(a[kc], bp[kc * 4], c, 0, 0, 0);
      int col = nt * 16 + l16;
      float bv = qb1[col];
#pragma unroll
      for (int r2 = 0; r2 < 4; ++r2) {
        int m = m0 + w * 16 + quad * 4 + r2;
        qkvout[(size_t)m * 384 + col] = f2b(c[r2] + bv);
      }
    }
  }
}

// ---------- fused proj(l1) + LayerNorm + NCHW store ----------
__global__ __launch_bounds__(256) void proj_ln(const unsigned short* __restrict__ attnp,
                                               const unsigned short* __restrict__ wp1,
                                               const float* __restrict__ pb1,
                                               const float* __restrict__ g,
                                               const float* __restrict__ bta,
                                               float* __restrict__ out) {
  __shared__ float tile[64][129];
  __shared__ float mean_s[64], rstd_s[64];
  int blk = blockIdx.x;            // b*64 + i  (row of 64 pixels)
  int b = blk >> 6, i = blk & 63;
  int m0 = blk * 64;
  int tid = threadIdx.x;
  int w = tid >> 6, lane = tid & 63;
  int quad = lane >> 4, l16 = lane & 15;

  // phase 1: proj -> fp32 LDS tile [pixel j][channel c]
  {
    const short8* ap =
        (const short8*)(attnp + (size_t)(m0 + w * 16 + l16) * 128 + quad * 8);
    short8 a[4];
#pragma unroll
    for (int kc = 0; kc < 4; ++kc) a[kc] = ap[kc * 4];
#pragma unroll
    for (int nt = 0; nt < 8; ++nt) {
      const short8* bp =
          (const short8*)(wp1 + (size_t)(nt * 16 + l16) * 128 + quad * 8);
      f32x4 c = {0.f, 0.f, 0.f, 0.f};
#pragma unroll
      for (int kc = 0; kc < 4; ++kc)
        c = __builtin_amdgcn_mfma_f32_16x16x32_bf16(a[kc], bp[kc * 4], c, 0, 0, 0);
      float bv = pb1[nt * 16 + l16];
#pragma unroll
      for (int r2 = 0; r2 < 4; ++r2)
        tile[w * 16 + quad * 4 + r2][nt * 16 + l16] = c[r2] + bv;
    }
  }
  __syncthreads();

  // phase 2: LN stats (4 threads per pixel)
  int jj = tid >> 2, qtr = tid & 3;
  float sum = 0.f, sumsq = 0.f;
#pragma unroll
  for (int cc = 0; cc < 32; ++cc) {
    float v = tile[jj][qtr * 32 + cc];
    sum += v; sumsq += v * v;
  }
  sum += __shfl_xor(sum, 1);  sum += __shfl_xor(sum, 2);
  sumsq += __shfl_xor(sumsq, 1);  sumsq += __shfl_xor(sumsq, 2);
  if (qtr == 0) {
    float mu = sum * (1.f / 128.f);
    mean_s[jj] = mu;
    rstd_s[jj] = rsqrtf(sumsq * (1.f / 128.f) - mu * mu + 1e-5f);
  }
  __syncthreads();

  // phase 3: normalized NCHW store, coalesced along j
  int c0 = tid >> 6;
  int j = tid & 63;
  for (int c = c0; c < 128; c += 4) {
    float v = (tile[j][c] - mean_s[j]) * rstd_s[j] * g[c] + bta[c];
    out[(((size_t)b * 128 + c) * 64 + i) * 64 + j] = v;
  }
}

extern "C" void kernel_launch(void* const* d_in, const int* in_sizes, int n_in,
                              void* d_out, int out_size, void* d_ws, size_t ws_size,
                              hipStream_t stream) {
  (void)in_sizes; (void)n_in; (void)out_size; (void)ws_size;
  const float* x   = (const float*)d_in[0];
  const float* qw  = (const float*)d_in[1];   // (2,384,128)
  const float* qb  = (const float*)d_in[2];   // (2,384)
  const float* rpb = (const float*)d_in[3];   // (2,4,13,13)
  const float* pw  = (const float*)d_in[4];   // (2,128,128)
  const float* pb  = (const float*)d_in[5];   // (2,128)
  const float* lg  = (const float*)d_in[6];
  const float* lb  = (const float*)d_in[7];

  unsigned short* ya   = (unsigned short*)d_ws;          // y0 then attn (2 MB)
  unsigned short* qkv  = ya + (size_t)PIX * 128;         // PIX*384 (6 MB)
  unsigned short* wq   = qkv + (size_t)PIX * 384;        // 98304
  unsigned short* wp   = wq + 98304;                     // 32768
  float* out = (float*)d_out;

  prep<<<512, 256, 0, stream>>>(x, qw, pw, ya, wq, wp);
  gemm_mfma<<<dim3(128, 6), 256, 0, stream>>>(ya, wq, qb, qkv, 384);      // qkv0 (reads y0)
  na_attn<<<dim3(128, 2, 2), 256, 0, stream>>>(qkv, rpb, ya);             // attn0 -> ya
  projqkv<<<128, 256, 0, stream>>>(ya, wp, pb, wq + 49152, qb + 384, qkv);// proj0+qkv1
  na_attn<<<dim3(128, 2, 2), 256, 0, stream>>>(qkv, rpb + 676, ya);       // attn1 -> ya
  proj_ln<<<128, 256, 0, stream>>>(ya, wp + 16384, pb + 128, lg, lb, out);// proj1+LN
}